// Round 11
// baseline (449.982 us; speedup 1.0000x reference)
//
#include <hip/hip_runtime.h>
#include <math.h>

// LIF_13984413516471 — exact serial chain; x/M staged in lane registers,
// broadcast via v_readlane; hierarchical certified quiet fast paths
// (64-t group / 8-t window) + exact margin-free per-t prefix check in
// busy windows. B=128, S=128, H=128, K=8.
// Reference: one scalar accumulator per batch, sequential over (i,j,k);
// per substep: s += x; if (s > th[k]) s = 0.
// Outputs (B,S,K,H) fp32: outs | spikes. Bitwise-exact fp32 replay.

#define NB 128
#define NS 128
#define NH 128
#define NK 8
#define NT (NS * NH)            // 16384 t per batch
#define WL 8                    // vote window = 8 t (64 substeps)
#define NW2 (NT / WL)           // 2048 windows per batch
#define NG64 (NT / 64)          // 256 groups (64 t = 8 windows each)
#define NP64 (NW2 / 64)         // 32 store-groups (64 windows = 512 t each)
#define OUTN ((size_t)NB * NS * NK * NH)

// ---- ws layout (floats) ----
#define WS_M     0                            // M    [NB][NW2]
#define WS_M64   (NB * NW2)                   // M64  [NB][NG64]
#define WS_SENT  (NB * NW2 + NB * NG64)       // s_ent[NB][NW2]
#define WS_TOTAL (2 * NB * NW2 + NB * NG64)

// Per-(b,window) and per-(b,group) quiet bounds, f64, RELATIVE to the
// threshold active at each substep: wmax = max_i (prefix_i - th_k(i)).
// Quiet iff entering s <= -wmax - margin: real-arith chain then stays
// >= margin below every active threshold; fp32 drift over n adds at
// |s|<=16384 is n*4.9e-4/2 (64->0.016, 512->0.125), covered by margins
// 0.1 / 0.5 with >=2x slack -> pure adds are bitwise-exact.
__global__ void lif_bounds(const float* __restrict__ x,
                           const float* __restrict__ th,
                           float* __restrict__ M, float* __restrict__ M64)
{
    int idx = blockIdx.x * 256 + threadIdx.x;   // flat over NB*NG64
    if (idx >= NB * NG64) return;
    int b = idx >> 8, gg = idx & (NG64 - 1);
    float t[NK];
#pragma unroll
    for (int k = 0; k < NK; ++k) t[k] = th[k];
    const float* xp = x + (size_t)b * NT + gg * 64;

    double pg = 0.0, gmax = -1e300;
#pragma unroll
    for (int w8 = 0; w8 < 8; ++w8) {
        double pw = 0.0, wmax = -1e300;
#pragma unroll
        for (int l = 0; l < 8; ++l) {
            double xv = (double)xp[w8 * 8 + l];
#pragma unroll
            for (int k = 0; k < NK; ++k) {
                pw += xv;
                double rel = pw - (double)t[k];
                wmax = fmax(wmax, rel);
            }
        }
        gmax = fmax(gmax, pg + wmax);
        pg += pw;
        M[(size_t)b * NW2 + gg * 8 + w8] =
            (float)(-wmax - 0.1 - 1e-6 * fabs(wmax));
    }
    M64[(size_t)b * NG64 + gg] = (float)(-gmax - 0.5 - 1e-6 * fabs(gmax));
}

#define ADD8(xv) do { s += xv; s += xv; s += xv; s += xv; \
                      s += xv; s += xv; s += xv; s += xv; } while (0)
#define STEP8(xv) do { \
    s += xv; s = (s > th0) ? 0.0f : s; \
    s += xv; s = (s > th1) ? 0.0f : s; \
    s += xv; s = (s > th2) ? 0.0f : s; \
    s += xv; s = (s > th3) ? 0.0f : s; \
    s += xv; s = (s > th4) ? 0.0f : s; \
    s += xv; s = (s > th5) ? 0.0f : s; \
    s += xv; s = (s > th6) ? 0.0f : s; \
    s += xv; s = (s > th7) ? 0.0f : s; } while (0)

__device__ __forceinline__ float rl(float v, int idx) {
    return __int_as_float(__builtin_amdgcn_readlane(__float_as_int(v), idx));
}

// Chain: 1 batch per 64-thread block (1 wave); all lanes run the scalar
// chain redundantly. Lane l of x-group g holds x[g*64+l]; values broadcast
// via readlane (SGPR operand of the dependent v_add chain, no waitcnt).
// Three tiers:
//   group-quiet (certified, 1 vote / 512 substeps): pure adds.
//   window-quiet (certified, 1 vote / 64 substeps): pure adds.
//   busy window: per-t EXACT prefix check — pure prefixes p1..p8 kept,
//     spike iff max_k(p_k - th_k) > 0 (fp32 subtract sign is exact, so
//     detection is margin-free and exact; before the first spike the
//     reset-chain equals the prefix chain bitwise). No spike: s = p8.
//     Spike (rare, uniform branch): exact STEP8 recompute of this t.
// Window-entry states collect per lane (cndmask) -> one coalesced store
// per 64 windows.
__global__ void __launch_bounds__(64, 1)
lif_chain(const float* __restrict__ x, const float* __restrict__ th,
          const float* __restrict__ M, const float* __restrict__ M64,
          float* __restrict__ s_ent)
{
    const int b = blockIdx.x;
    const int lane = threadIdx.x;
    const float* xb   = x + (size_t)b * NT;
    const float* Mb   = M + (size_t)b * NW2;
    const float* M64b = M64 + (size_t)b * NG64;
    float* seb = s_ent + (size_t)b * NW2;

    const float th0 = th[0], th1 = th[1], th2 = th[2], th3 = th[3];
    const float th4 = th[4], th5 = th[5], th6 = th[6], th7 = th[7];

    float s = 0.0f, keep = 0.0f;
    float cx   = xb[lane];      // x-group 0 (64 t = 8 windows)
    float cM   = Mb[lane];      // window bounds, store-group 0
    float cM64 = M64b[0];       // group bound 0

    for (int p = 0; p < NP64; ++p) {
        float nM = Mb[(size_t)((p + 1 < NP64) ? p + 1 : p) * 64 + lane];
        for (int g8 = 0; g8 < 8; ++g8) {
            const int gg = p * 8 + g8;
            const int ggn = (gg + 1 < NG64) ? gg + 1 : gg;
            float nx   = xb[(size_t)ggn * 64 + lane];
            float nM64 = M64b[ggn];
            const int wbase = g8 * 8;

            int q64 = __builtin_amdgcn_readfirstlane((int)(s <= cM64));
            if (q64) {
                // certified spike-free 64-t group: 512 bitwise-exact adds
                float xc = rl(cx, 0);
#pragma unroll
                for (int wi = 0; wi < 8; ++wi) {
                    keep = (lane == wbase + wi) ? s : keep;
#pragma unroll
                    for (int m = 0; m < 8; ++m) {
                        int ni = wi * 8 + m + 1; if (ni > 63) ni = 63;
                        float xn = rl(cx, ni);
                        ADD8(xc);
                        xc = xn;
                    }
                }
            } else {
#pragma unroll
                for (int wi = 0; wi < 8; ++wi) {
                    float Mc = rl(cM, wbase + wi);
                    keep = (lane == wbase + wi) ? s : keep;
                    int q = __builtin_amdgcn_readfirstlane((int)(s <= Mc));
                    if (q) {
                        // certified spike-free window: pure adds
                        float xc = rl(cx, wi * 8);
#pragma unroll
                        for (int m = 0; m < 8; ++m) {
                            int ni = wi * 8 + m + 1; if (ni > 63) ni = 63;
                            float xn = rl(cx, ni);
                            ADD8(xc);
                            xc = xn;
                        }
                    } else {
                        // busy window: exact per-t prefix check
#pragma unroll
                        for (int m = 0; m < 8; ++m) {
                            float xc = rl(cx, wi * 8 + m);
                            float p1 = s  + xc, p2 = p1 + xc;
                            float p3 = p2 + xc, p4 = p3 + xc;
                            float p5 = p4 + xc, p6 = p5 + xc;
                            float p7 = p6 + xc, p8 = p7 + xc;
                            float d1 = fmaxf(fmaxf(p1 - th0, p2 - th1),
                                             fmaxf(p3 - th2, p4 - th3));
                            float d2 = fmaxf(fmaxf(p5 - th4, p6 - th5),
                                             fmaxf(p7 - th6, p8 - th7));
                            int sp = __builtin_amdgcn_readfirstlane(
                                         (int)(fmaxf(d1, d2) > 0.0f));
                            if (sp) {
                                STEP8(xc);   // exact resets, rare
                            } else {
                                s = p8;      // bitwise equal to reset-chain
                            }
                        }
                    }
                }
            }
            cx = nx; cM64 = nM64;
        }
        seb[(size_t)p * 64 + lane] = keep;              // coalesced, 1/64 windows
        cM = nM;
    }
}

// Output pass: fully parallel, no serial section. block = (b, i), thread j.
// Lane j replays (j&7) t-steps from its window's entering state, then emits
// its own t's 8 outputs, coalesced per k-plane. Bitwise-exact replay.
__global__ void __launch_bounds__(128)
lif_out(const float* __restrict__ x, const float* __restrict__ th,
        const float* __restrict__ s_ent, float* __restrict__ out)
{
    const int j = threadIdx.x;             // 0..127
    const int i = blockIdx.x & (NS - 1);
    const int b = blockIdx.x >> 7;
    const int wl = j >> 3;                 // window within row (0..15)
    const int r  = j & 7;                  // position within window

    const float th0 = th[0], th1 = th[1], th2 = th[2], th3 = th[3];
    const float th4 = th[4], th5 = th[5], th6 = th[6], th7 = th[7];

    float s = s_ent[(size_t)b * NW2 + i * 16 + wl];
    const float* xrow = x + (size_t)b * NT + i * NH + (wl << 3);

    for (int m = 0; m < r; ++m) {          // replay to own t (<=7 steps)
        float xv = xrow[m];
        STEP8(xv);
    }
    float xv = xrow[r];

    float* o  = out + (((size_t)b * NS + i) * NK) * NH + j;
    float* sp = o + OUTN;
    float thr[NK];
#pragma unroll
    for (int k = 0; k < NK; ++k) thr[k] = th[k];
#pragma unroll
    for (int k = 0; k < NK; ++k) {
        s += xv;
        bool spike = s > thr[k];
        o[(size_t)k * NH]  = spike ? s : 0.0f;
        sp[(size_t)k * NH] = spike ? 1.0f : 0.0f;
        s = spike ? 0.0f : s;
    }
}

// Fallback if ws is too small: single-pass, scattered writes (slow, correct).
__global__ void lif_mono(const float* __restrict__ x, const float* __restrict__ th,
                         float* __restrict__ out)
{
    int b = blockIdx.x * 64 + threadIdx.x;
    if (b >= NB) return;
    float thr[NK];
#pragma unroll
    for (int k = 0; k < NK; ++k) thr[k] = th[k];
    const float* xb = x + (size_t)b * NT;
    float s = 0.0f;
    for (int i = 0; i < NS; ++i)
        for (int j = 0; j < NH; ++j) {
            float xv = xb[i * NH + j];
#pragma unroll
            for (int k = 0; k < NK; ++k) {
                s += xv;
                bool spike = s > thr[k];
                size_t idx = (((size_t)b * NS + i) * NK + k) * NH + j;
                out[idx]        = spike ? s : 0.0f;
                out[OUTN + idx] = spike ? 1.0f : 0.0f;
                s = spike ? 0.0f : s;
            }
        }
}

extern "C" void kernel_launch(void* const* d_in, const int* in_sizes, int n_in,
                              void* d_out, int out_size, void* d_ws, size_t ws_size,
                              hipStream_t stream) {
    const float* x  = (const float*)d_in[0];   // (128,128,128) fp32
    const float* th = (const float*)d_in[1];   // (8,) fp32
    float* out = (float*)d_out;

    if (ws_size >= (size_t)WS_TOTAL * sizeof(float)) {
        float* ws    = (float*)d_ws;
        float* Mbuf  = ws + WS_M;
        float* M64b  = ws + WS_M64;
        float* s_ent = ws + WS_SENT;

        lif_bounds<<<dim3((NB * NG64 + 255) / 256), dim3(256), 0, stream>>>(x, th, Mbuf, M64b);
        lif_chain<<<dim3(NB), dim3(64), 0, stream>>>(x, th, Mbuf, M64b, s_ent);
        lif_out<<<dim3(NB * NS), dim3(128), 0, stream>>>(x, th, s_ent, out);
    } else {
        lif_mono<<<dim3(2), dim3(64), 0, stream>>>(x, th, out);
    }
}